// Round 1
// baseline (356.819 us; speedup 1.0000x reference)
//
#include <hip/hip_runtime.h>
#include <hip/hip_bf16.h>
#include <cstdint>
#include <cstddef>

// MoE expert FFN: h = gelu(x @ w1[e]^T + b1[e]); out = h @ w2[e]^T + b2[e]
// Strategy: f32->bf16 convert pass into ws, then two grouped bf16-MFMA GEMMs
// (m97 structure: 128x128 tile, BK=32, global_load_lds width=16, 2-phase dbuf).

typedef __bf16 bf16x8 __attribute__((ext_vector_type(8)));
typedef float f32x4 __attribute__((ext_vector_type(4)));
typedef unsigned short u16x8 __attribute__((ext_vector_type(8)));

#define BM 128
#define BN 128
#define BK 32

__device__ __forceinline__ unsigned short f2bf(float f) {
  unsigned u = __builtin_bit_cast(unsigned, f);
  u += 0x7FFFu + ((u >> 16) & 1u);   // RNE
  return (unsigned short)(u >> 16);
}

__device__ __forceinline__ void gload16(const void* g, void* lds) {
  __builtin_amdgcn_global_load_lds(
      (const __attribute__((address_space(1))) void*)g,
      (__attribute__((address_space(3))) void*)lds, 16, 0, 0);
}

// ---------------- setup: tile table from expert counts ----------------
__global__ void build_tiles(const int* __restrict__ cnt, int E,
                            int4* __restrict__ tbl, int* __restrict__ ntp) {
  if (threadIdx.x == 0 && blockIdx.x == 0) {
    int nt = 0, start = 0;
    for (int e = 0; e < E; ++e) {
      int c = cnt[e];
      for (int t = 0; t < c; t += BM) {
        int4 v;
        v.x = e; v.y = start + t; v.z = (c - t < BM ? c - t : BM); v.w = 0;
        tbl[nt++] = v;
      }
      start += c;
    }
    *ntp = nt;
  }
}

// ---------------- f32 -> bf16 convert (vectorized, 8/thread/iter) ------
__global__ void cvt_kernel(const float* __restrict__ src,
                           unsigned short* __restrict__ dst, long n) {
  long i = ((long)blockIdx.x * blockDim.x + threadIdx.x) * 8;
  const long stride = (long)gridDim.x * blockDim.x * 8;
  for (; i < n; i += stride) {
    float4 a = *reinterpret_cast<const float4*>(src + i);
    float4 b = *reinterpret_cast<const float4*>(src + i + 4);
    u16x8 o;
    o[0] = f2bf(a.x); o[1] = f2bf(a.y); o[2] = f2bf(a.z); o[3] = f2bf(a.w);
    o[4] = f2bf(b.x); o[5] = f2bf(b.y); o[6] = f2bf(b.z); o[7] = f2bf(b.w);
    *reinterpret_cast<u16x8*>(dst + i) = o;
  }
}

// ---------------- grouped GEMM: C[t, n] = A[t, :] . W[e][n, :] ---------
// A: [T, K] bf16 row-major, W: [E, N, K] bf16 (K contiguous, "B^T" case),
// bias: [E, N] f32. GELU: apply exact gelu. OUTBF: write bf16 else f32.
template <int GELU, int OUTBF>
__global__ __launch_bounds__(256, 2) void grouped_gemm(
    const unsigned short* __restrict__ A, const unsigned short* __restrict__ W,
    const float* __restrict__ bias, void* __restrict__ Cv,
    const int4* __restrict__ tbl, const int* __restrict__ ntp,
    const int N, const int K) {
  const int mt = blockIdx.y;
  if (mt >= *ntp) return;
  const int4 ti = tbl[mt];
  const int e = ti.x, row0 = ti.y, rows = ti.z;
  const int bcol = blockIdx.x * BN;

  __shared__ unsigned short sA[2][BM * BK];
  __shared__ unsigned short sB[2][BN * BK];

  const int tid = threadIdx.x;
  const int lane = tid & 63;
  const int wave = tid >> 6;
  const int wr = wave >> 1;  // wave row (0..1), 64 rows each
  const int wc = wave & 1;   // wave col (0..1), 64 cols each

  const unsigned short* __restrict__ Wexp = W + (size_t)e * N * K;

  // Staging: per K-step the block loads A-tile 128x32 (8KB) + B-tile (8KB).
  // One global_load_lds(16B) per wave covers 1KB = 16 rows; chunk i (+4KB)
  // covers rows i*64..i*64+63. Linear LDS layout [row][k].
  const int srow = wave * 16 + (lane >> 2);  // + i*64
  const int skoff = (lane & 3) * 8;          // k elements within row
  const int a0 = srow < rows ? srow : rows - 1;          // clamp inside segment
  const int a1 = srow + 64 < rows ? srow + 64 : rows - 1;
  const unsigned short* gA0 = A + (size_t)(row0 + a0) * K + skoff;
  const unsigned short* gA1 = A + (size_t)(row0 + a1) * K + skoff;
  const unsigned short* gB0 = Wexp + (size_t)(bcol + srow) * K + skoff;
  const unsigned short* gB1 = Wexp + (size_t)(bcol + srow + 64) * K + skoff;

  f32x4 acc[4][4] = {};
  const int aRowB = wr * 64 + (lane & 15);
  const int bRowB = wc * 64 + (lane & 15);
  const int kHalf = (lane >> 4) * 8;

  const int nk = K / BK;
  // prologue stage
  {
    char* da = (char*)&sA[0][0] + wave * 1024;
    char* db = (char*)&sB[0][0] + wave * 1024;
    gload16(gA0, da);
    gload16(gA1, da + 4096);
    gload16(gB0, db);
    gload16(gB1, db + 4096);
  }
  __syncthreads();

  int buf = 0;
  for (int t = 0; t < nk; ++t) {
    if (t + 1 < nk) {
      const int k0 = (t + 1) * BK;
      char* da = (char*)&sA[buf ^ 1][0] + wave * 1024;
      char* db = (char*)&sB[buf ^ 1][0] + wave * 1024;
      gload16(gA0 + k0, da);
      gload16(gA1 + k0, da + 4096);
      gload16(gB0 + k0, db);
      gload16(gB1 + k0, db + 4096);
    }
    bf16x8 af[4], bfr[4];
#pragma unroll
    for (int m = 0; m < 4; ++m)
      af[m] = *reinterpret_cast<const bf16x8*>(&sA[buf][(aRowB + m * 16) * BK + kHalf]);
#pragma unroll
    for (int n = 0; n < 4; ++n)
      bfr[n] = *reinterpret_cast<const bf16x8*>(&sB[buf][(bRowB + n * 16) * BK + kHalf]);
#pragma unroll
    for (int m = 0; m < 4; ++m)
#pragma unroll
      for (int n = 0; n < 4; ++n)
        acc[m][n] = __builtin_amdgcn_mfma_f32_16x16x32_bf16(af[m], bfr[n], acc[m][n], 0, 0, 0);
    __syncthreads();  // drains prefetch vmcnt + barrier (buffer handoff)
    buf ^= 1;
  }

  // epilogue: bias (+gelu) and store.
  // C/D layout (m89-verified): col = lane&15, row = (lane>>4)*4 + reg.
  const float* __restrict__ be = bias + (size_t)e * N;
  const int colBase = bcol + wc * 64 + (lane & 15);
  const int rowBase = wr * 64 + ((lane >> 4) << 2);
#pragma unroll
  for (int n = 0; n < 4; ++n) {
    const int col = colBase + n * 16;
    const float bv = be[col];
#pragma unroll
    for (int m = 0; m < 4; ++m) {
      const int r0 = rowBase + m * 16;
#pragma unroll
      for (int j = 0; j < 4; ++j) {
        const int r = r0 + j;
        if (r < rows) {
          float v = acc[m][n][j] + bv;
          if (GELU) v = 0.5f * v * (1.0f + erff(v * 0.7071067811865476f));
          if (OUTBF)
            ((unsigned short*)Cv)[(size_t)(row0 + r) * N + col] = f2bf(v);
          else
            ((float*)Cv)[(size_t)(row0 + r) * N + col] = v;
        }
      }
    }
  }
}

extern "C" void kernel_launch(void* const* d_in, const int* in_sizes, int n_in,
                              void* d_out, int out_size, void* d_ws, size_t ws_size,
                              hipStream_t stream) {
  const float* inp = (const float*)d_in[0];
  const float* w1  = (const float*)d_in[1];
  const float* b1  = (const float*)d_in[2];
  const float* w2  = (const float*)d_in[3];
  const float* b2  = (const float*)d_in[4];
  const int*   cnt = (const int*)d_in[5];

  const int E = in_sizes[5];
  const int H = in_sizes[2] / E;       // b1 is [E,H]
  const int D = in_sizes[4] / E;       // b2 is [E,D]
  const int T = in_sizes[0] / D;       // inp is [T,D]

  char* ws = (char*)d_ws;
  int4* tbl = (int4*)ws;               // up to 128 tile entries (need <=72)
  int* ntp = (int*)(ws + 2048);
  size_t off = 4096;
  unsigned short* inp_bf = (unsigned short*)(ws + off); off += (size_t)T * D * 2;
  unsigned short* w1_bf  = (unsigned short*)(ws + off); off += (size_t)E * H * D * 2;
  unsigned short* w2_bf  = (unsigned short*)(ws + off); off += (size_t)E * D * H * 2;
  unsigned short* h_bf   = (unsigned short*)(ws + off); off += (size_t)T * H * 2;
  (void)ws_size; (void)n_in; (void)out_size;

  build_tiles<<<1, 64, 0, stream>>>(cnt, E, tbl, ntp);

  cvt_kernel<<<2048, 256, 0, stream>>>(inp, inp_bf, (long)T * D);
  cvt_kernel<<<2048, 256, 0, stream>>>(w1, w1_bf, (long)E * H * D);
  cvt_kernel<<<2048, 256, 0, stream>>>(w2, w2_bf, (long)E * D * H);

  const int maxTiles = T / BM + E;     // covers any count distribution
  dim3 g1(H / BN, maxTiles);
  grouped_gemm<1, 1><<<g1, 256, 0, stream>>>(inp_bf, w1_bf, b1, h_bf, tbl, ntp, H, D);
  dim3 g2(D / BN, maxTiles);
  grouped_gemm<0, 0><<<g2, 256, 0, stream>>>(h_bf, w2_bf, b2, d_out, tbl, ntp, D, H);
}